// Round 10
// baseline (271.777 us; speedup 1.0000x reference)
//
#include <hip/hip_runtime.h>
#include <cmath>

#define M_ROWS  65536
#define D_DIM   64
#define K_CODES 4096

// d_out float offsets (z_q_st | indices | vq_loss | perplexity | z_q)
#define OFF_IDX  4194304
#define OFF_SCAL 4259840
#define OFF_ZQ   4259842

// scratch regions inside d_out (consumed before their region is written)
#define IMG_OFF   (4u << 20)                 // codebook image, 1 MB (in z_q_st region)
#define E2B_OFF   (IMG_OFF + 1048576u)       // e2+32 array, 16 KB
#define CANDB_OFF 17039368u                  // == OFF_ZQ*4 : fallback cand64 (8 MB, overwritten by zq_kernel)

// codebook chunk image: 128 codes, bf16 hi/lo split, 128 B/row, XOR-swizzled granules
#define CH_LO    16384
#define CH_BYTES 32768
#define CH_QUADS 2048
#define NSPLIT   4
#define NCHB     8                            // chunks per block (1024 codes)

typedef __attribute__((ext_vector_type(8))) short s16x8;
typedef __attribute__((ext_vector_type(4))) float f32x4;
typedef unsigned long long u64;

__device__ __forceinline__ unsigned short f2bf(float f) {   // RNE float->bf16 bits
  unsigned int u = __float_as_uint(f);
  return (unsigned short)((u + 0x7FFFu + ((u >> 16) & 1u)) >> 16);
}
__device__ __forceinline__ float bf2f(unsigned short h) {
  return __uint_as_float(((unsigned int)h) << 16);
}
__device__ __forceinline__ unsigned int umin_(unsigned int a, unsigned int b) {
  return a < b ? a : b;
}
// second-min update: with invariant b1 <= b2, new b2 = median(old b1, b2, key)
__device__ __forceinline__ unsigned int med3_u32(unsigned int a, unsigned int b, unsigned int c) {
  unsigned int d;
  asm("v_med3_u32 %0, %1, %2, %3" : "=v"(d) : "v"(a), "v"(b), "v"(c));
  return d;
}

// ---------------------------------------------------------------------------
// K1a: e2[k] exact (numpy 8-accumulator pairwise pattern)
// ---------------------------------------------------------------------------
__global__ void e2_kernel(const float* __restrict__ cb,
                          float* __restrict__ e2, float* __restrict__ e2b) {
  int k = blockIdx.x * 256 + threadIdx.x;
  if (k >= K_CODES) return;
  const float4* row = (const float4*)(cb + (size_t)k * D_DIM);
  float4 q[16];
#pragma unroll
  for (int i = 0; i < 16; ++i) q[i] = row[i];
  float s;
  {
#pragma clang fp contract(off)
    float r[8];
    {
      const float* f = (const float*)&q[0];
#pragma unroll
      for (int j = 0; j < 8; ++j) r[j] = f[j] * f[j];
    }
#pragma unroll
    for (int a = 1; a < 8; ++a) {
      const float* f = (const float*)&q[2 * a];
#pragma unroll
      for (int j = 0; j < 8; ++j) r[j] = r[j] + f[j] * f[j];
    }
    s = ((r[0] + r[1]) + (r[2] + r[3])) + ((r[4] + r[5]) + (r[6] + r[7]));
  }
  e2[k] = s;
  e2b[k] = s + 32.0f;
}

// ---------------------------------------------------------------------------
// K1b: bf16 hi/lo split image, fully coalesced; granule g at ((g+r)&7)
// ---------------------------------------------------------------------------
__global__ void img_kernel(const float* __restrict__ cb, char* __restrict__ img) {
  int t = blockIdx.x * 256 + threadIdx.x;   // 65536 threads, 4 elements each
  int k  = t >> 4;
  int d0 = (t & 15) * 4;
  float4 f = ((const float4*)cb)[t];
  ushort4 hi, lo;
  hi.x = f2bf(f.x); lo.x = f2bf(f.x - bf2f(hi.x));
  hi.y = f2bf(f.y); lo.y = f2bf(f.y - bf2f(hi.y));
  hi.z = f2bf(f.z); lo.z = f2bf(f.z - bf2f(hi.z));
  hi.w = f2bf(f.w); lo.w = f2bf(f.w - bf2f(hi.w));
  int c = k >> 7, r = k & 127;
  int g = d0 >> 3;
  int off = ((g + r) & 7) * 16 + (d0 & 7) * 2;
  char* base = img + (size_t)c * CH_BYTES + r * 128;
  *(ushort4*)(base + off) = hi;
  *(ushort4*)(base + CH_LO + off) = lo;
}

// ---------------------------------------------------------------------------
// K2: MFMA distance pass — round-6 measured-best body (NSPLIT 4, 512 thr,
// grid 512, 64 VGPR no spill). Only change: final store is column-major u64
// cand64[slot*M + row], slot = sp*4+i (16 slots).
// ---------------------------------------------------------------------------
__global__ __launch_bounds__(512, 4)
void vq_mfma_kernel(const float* __restrict__ z_e,
                    const char* __restrict__ img,
                    const float* __restrict__ e2b,
                    u64* __restrict__ cand64) {
  __shared__ union {
    uint4 q[CH_QUADS];
    char raw[CH_BYTES];
    unsigned int cand[256 * 33];     // 33792 B
  } sm;
  __shared__ float lds_e2[128];
  const int tid  = threadIdx.x;
  const int wave = tid >> 6, lane = tid & 63;
  const int quad = lane >> 4, c16 = lane & 15;
  const int rb   = blockIdx.x >> 2;           // row-group of 512
  const int sp   = blockIdx.x & 3;            // K-split id
  const int mb   = rb * 512 + wave * 64;

  // A-fragments: 4 row-tiles x (k-halves) x (hi/lo), A[m=lane&15][k=quad*8+j]
  s16x8 zh[4][2], zl[4][2];
#pragma unroll
  for (int mt = 0; mt < 4; ++mt) {
    int m = mb + mt * 16 + c16;
#pragma unroll
    for (int s = 0; s < 2; ++s) {
      const float* zp = z_e + (size_t)m * 64 + s * 32 + quad * 8;
      float4 fa = ((const float4*)zp)[0];
      float4 fb = ((const float4*)zp)[1];
      float v[8] = {fa.x, fa.y, fa.z, fa.w, fb.x, fb.y, fb.z, fb.w};
      union { s16x8 v8; unsigned short e[8]; } H, L;
#pragma unroll
      for (int j = 0; j < 8; ++j) {
        float f = -2.0f * v[j];
        unsigned short h = f2bf(f);
        H.e[j] = h;
        L.e[j] = f2bf(f - bf2f(h));
      }
      zh[mt][s] = H.v8;
      zl[mt][s] = L.v8;
    }
  }

  unsigned int b1[4][4], b2[4][4];
#pragma unroll
  for (int mt = 0; mt < 4; ++mt)
#pragma unroll
    for (int r = 0; r < 4; ++r) { b1[mt][r] = 0xFFFFFFFFu; b2[mt][r] = 0xFFFFFFFFu; }

  const int swz0 = ((quad + c16) & 7) * 16;       // t-invariant swizzle offsets
  const int swz1 = ((quad + 4 + c16) & 7) * 16;

  for (int c = 0; c < NCHB; ++c) {
    __syncthreads();
    {
      const uint4* src = (const uint4*)(img + (size_t)(sp * NCHB + c) * CH_BYTES);
#pragma unroll
      for (int i = 0; i < 4; ++i) sm.q[tid + i * 512] = src[tid + i * 512];
      if (tid < 128) lds_e2[tid] = e2b[sp * 1024 + c * 128 + tid];
    }
    __syncthreads();

#pragma unroll 1
    for (int t = 0; t < 8; ++t) {
      const char* hb = sm.raw + (t * 16 + c16) * 128;
      s16x8 Bh0 = *(const s16x8*)(hb + swz0);
      s16x8 Bh1 = *(const s16x8*)(hb + swz1);
      s16x8 Bl0 = *(const s16x8*)(hb + CH_LO + swz0);
      s16x8 Bl1 = *(const s16x8*)(hb + CH_LO + swz1);
      float e2v = lds_e2[t * 16 + c16];
      unsigned int tid8 = (unsigned int)(sp * 64 + c * 8 + t);  // global 16-code tile id
      f32x4 cvec = {e2v, e2v, e2v, e2v};

#pragma unroll
      for (int mt = 0; mt < 4; ++mt) {
        f32x4 acc;
        acc = __builtin_amdgcn_mfma_f32_16x16x32_bf16(zh[mt][0], Bh0, cvec, 0, 0, 0);
        acc = __builtin_amdgcn_mfma_f32_16x16x32_bf16(zh[mt][1], Bh1, acc, 0, 0, 0);
        acc = __builtin_amdgcn_mfma_f32_16x16x32_bf16(zl[mt][0], Bh0, acc, 0, 0, 0);
        acc = __builtin_amdgcn_mfma_f32_16x16x32_bf16(zl[mt][1], Bh1, acc, 0, 0, 0);
        acc = __builtin_amdgcn_mfma_f32_16x16x32_bf16(zh[mt][0], Bl0, acc, 0, 0, 0);
        acc = __builtin_amdgcn_mfma_f32_16x16x32_bf16(zh[mt][1], Bl1, acc, 0, 0, 0);
#pragma unroll
        for (int r = 0; r < 4; ++r) {
          unsigned int key = (__float_as_uint(acc[r]) & 0xFFFFFF00u) | tid8;
          b2[mt][r] = med3_u32(b1[mt][r], b2[mt][r], key);
          b1[mt][r] = umin_(b1[mt][r], key);
        }
      }
    }
  }

  // final selection: two passes of 256 rows through the cand buffer
  for (int pass = 0; pass < 2; ++pass) {
    __syncthreads();
    if ((wave >> 2) == pass) {
      int wl = wave & 3;
#pragma unroll
      for (int mt = 0; mt < 4; ++mt)
#pragma unroll
        for (int r = 0; r < 4; ++r) {
          int lr = wl * 64 + mt * 16 + quad * 4 + r;   // C: col=lane&15, row=quad*4+reg
          sm.cand[lr * 33 + c16 * 2 + 0] = b1[mt][r];
          sm.cand[lr * 33 + c16 * 2 + 1] = b2[mt][r];
        }
    }
    __syncthreads();
    if (tid < 256) {
      unsigned int kk[4] = {0xFFFFFFFFu, 0xFFFFFFFFu, 0xFFFFFFFFu, 0xFFFFFFFFu};
      unsigned int vv[4] = {0, 0, 0, 0};
      for (int j = 0; j < 32; ++j) {
        unsigned int key = sm.cand[tid * 33 + j];
        if (key < kk[3]) {
          kk[3] = key;
          vv[3] = (key & 0xFFu) * 16 + (unsigned int)(j >> 1);  // k = tile*16 + col
          for (int p = 3; p > 0; --p)
            if (kk[p] < kk[p - 1]) {
              unsigned int a = kk[p]; kk[p] = kk[p - 1]; kk[p - 1] = a;
              unsigned int b = vv[p]; vv[p] = vv[p - 1]; vv[p - 1] = b;
            }
        }
      }
      int grow = rb * 512 + pass * 256 + tid;
#pragma unroll
      for (int i = 0; i < 4; ++i)
        cand64[(size_t)(sp * 4 + i) * M_ROWS + grow] = ((u64)kk[i] << 32) | (u64)vv[i];
    }
  }
}

// ---------------------------------------------------------------------------
// K3: pick. One thread/row; 16 coalesced cand loads -> global top-4 (exact:
// global top-4 is a subset of per-split top-4s). Gap gate 4 quanta: gated rows
// write idx (no cb/z access); ambiguous rows ballot-compacted to alist.
// ---------------------------------------------------------------------------
__global__ __launch_bounds__(256)
void pick_kernel(const u64* __restrict__ cand64, float* __restrict__ out,
                 int* __restrict__ cnt, int* __restrict__ alist) {
  const int tid = threadIdx.x;
  const int r   = blockIdx.x * 256 + tid;

  u64 t4[4] = {~0ull, ~0ull, ~0ull, ~0ull};
#pragma unroll 1
  for (int j = 0; j < 16; ++j) {
    u64 v = cand64[(size_t)j * M_ROWS + r];       // coalesced across lanes
    if (v < t4[3]) {
      t4[3] = v;
#pragma unroll
      for (int p = 3; p > 0; --p)
        if (t4[p] < t4[p - 1]) { u64 a = t4[p]; t4[p] = t4[p - 1]; t4[p - 1] = a; }
    }
  }

  unsigned int key1 = (unsigned int)(t4[0] >> 32) & 0xFFFFFF00u;
  unsigned int key2 = (unsigned int)(t4[1] >> 32) & 0xFFFFFF00u;
  bool ambig = (key2 - key1) < 1024u;             // < 4 quanta
  if (!ambig) out[OFF_IDX + r] = (float)(unsigned int)(t4[0] & 0xFFFFFFFFu);

  unsigned long long mb = __ballot(ambig);
  if (ambig) {
    int lane = tid & 63;
    int leader = __ffsll(mb) - 1;
    int base = 0;
    if (lane == leader) base = atomicAdd(cnt, __popcll(mb));
    base = __shfl(base, leader);
    int pos = __popcll(mb & ((1ull << lane) - 1ull));
    alist[base + pos] = r;
  }
}

// ---------------------------------------------------------------------------
// K4: resolve. Only ambiguous rows (~5%): serial exact check of top-4 with
// the bit-exact numpy formula (verified r2..r9), first-min tie-break.
// ---------------------------------------------------------------------------
__global__ __launch_bounds__(256)
void resolve_kernel(const float* __restrict__ z_e, const float* __restrict__ cb,
                    const float* __restrict__ e2, const u64* __restrict__ cand64,
                    const int* __restrict__ alist, const int* __restrict__ cnt,
                    float* __restrict__ out) {
  int i = blockIdx.x * 256 + threadIdx.x;
  if (i >= *cnt) return;
  int r = alist[i];

  u64 t4[4] = {~0ull, ~0ull, ~0ull, ~0ull};
#pragma unroll 1
  for (int j = 0; j < 16; ++j) {
    u64 v = cand64[(size_t)j * M_ROWS + r];
    if (v < t4[3]) {
      t4[3] = v;
#pragma unroll
      for (int p = 3; p > 0; --p)
        if (t4[p] < t4[p - 1]) { u64 a = t4[p]; t4[p] = t4[p - 1]; t4[p - 1] = a; }
    }
  }

  const float4* zr = (const float4*)(z_e + (size_t)r * 64);
  float4 z4[16];
#pragma unroll
  for (int j = 0; j < 16; ++j) z4[j] = zr[j];

  float z2;
  {
#pragma clang fp contract(off)
    float rr[8];
    {
      const float* f = (const float*)&z4[0];
#pragma unroll
      for (int j = 0; j < 8; ++j) rr[j] = f[j] * f[j];
    }
#pragma unroll
    for (int a = 1; a < 8; ++a) {
      const float* f = (const float*)&z4[2 * a];
#pragma unroll
      for (int j = 0; j < 8; ++j) rr[j] = rr[j] + f[j] * f[j];
    }
    z2 = ((rr[0] + rr[1]) + (rr[2] + rr[3])) + ((rr[4] + rr[5]) + (rr[6] + rr[7]));
  }

  float bd = INFINITY;
  int bk = K_CODES;
#pragma unroll 1
  for (int ci = 0; ci < 4; ++ci) {
    int k = (int)(unsigned int)(t4[ci] & 0xFFFFFFFFu);
    const float4* ev = (const float4*)(cb + (size_t)k * 64);
    float4 a0 = make_float4(0.f, 0.f, 0.f, 0.f);
    float4 a1 = make_float4(0.f, 0.f, 0.f, 0.f);
    float4 a2 = make_float4(0.f, 0.f, 0.f, 0.f);
    float4 a3 = make_float4(0.f, 0.f, 0.f, 0.f);
#pragma unroll
    for (int q = 0; q < 4; ++q) {
      float4 e0 = ev[4 * q + 0], e1 = ev[4 * q + 1], e2v = ev[4 * q + 2], e3 = ev[4 * q + 3];
      a0.x = fmaf(z4[4 * q + 0].x, e0.x, a0.x); a0.y = fmaf(z4[4 * q + 0].y, e0.y, a0.y);
      a0.z = fmaf(z4[4 * q + 0].z, e0.z, a0.z); a0.w = fmaf(z4[4 * q + 0].w, e0.w, a0.w);
      a1.x = fmaf(z4[4 * q + 1].x, e1.x, a1.x); a1.y = fmaf(z4[4 * q + 1].y, e1.y, a1.y);
      a1.z = fmaf(z4[4 * q + 1].z, e1.z, a1.z); a1.w = fmaf(z4[4 * q + 1].w, e1.w, a1.w);
      a2.x = fmaf(z4[4 * q + 2].x, e2v.x, a2.x); a2.y = fmaf(z4[4 * q + 2].y, e2v.y, a2.y);
      a2.z = fmaf(z4[4 * q + 2].z, e2v.z, a2.z); a2.w = fmaf(z4[4 * q + 2].w, e2v.w, a2.w);
      a3.x = fmaf(z4[4 * q + 3].x, e3.x, a3.x); a3.y = fmaf(z4[4 * q + 3].y, e3.y, a3.y);
      a3.z = fmaf(z4[4 * q + 3].z, e3.z, a3.z); a3.w = fmaf(z4[4 * q + 3].w, e3.w, a3.w);
    }
    float d;
    {
#pragma clang fp contract(off)
      float sx = (a0.x + a1.x) + (a2.x + a3.x);
      float sy = (a0.y + a1.y) + (a2.y + a3.y);
      float sz = (a0.z + a1.z) + (a2.z + a3.z);
      float sw = (a0.w + a1.w) + (a2.w + a3.w);
      float dot = (sx + sy) + (sz + sw);
      float tt = z2 + e2[k];
      d = tt - 2.0f * dot;
    }
    if (d < bd || (d == bd && k < bk)) { bd = d; bk = k; }
  }

  out[OFF_IDX + r] = (float)bk;
}

// ---------------------------------------------------------------------------
// K5: zq. 16 lanes per row: idx broadcast-read, winner gather is 4 cb rows
// per wave-inst (16 tx), z read + both outputs coalesced. Commit partials.
// ---------------------------------------------------------------------------
__global__ __launch_bounds__(256)
void zq_kernel(const float* __restrict__ z_e, const float* __restrict__ cb,
               float* __restrict__ out, double* __restrict__ partials) {
  const int tid = threadIdx.x;
  const int t   = blockIdx.x * 256 + tid;
  const int m   = t >> 4, seg = t & 15;

  int k = (int)out[OFF_IDX + m];
  float4 q = *(const float4*)(cb + (size_t)k * 64 + seg * 4);
  float4 z = *(const float4*)(z_e + (size_t)m * 64 + seg * 4);

  ((float4*)out)[(size_t)m * 16 + seg] = q;           // z_q_st
  float* d1 = out + OFF_ZQ + (size_t)m * 64 + seg * 4; // z_q (8B-aligned)
  ((float2*)d1)[0] = make_float2(q.x, q.y);
  ((float2*)d1)[1] = make_float2(q.z, q.w);

  float dx = z.x - q.x, dy = z.y - q.y, dz = z.z - q.z, dw = z.w - q.w;
  double csum = (double)dx * dx + (double)dy * dy + (double)dz * dz + (double)dw * dw;
#pragma unroll
  for (int off = 32; off > 0; off >>= 1) csum += __shfl_down(csum, off);
  if ((tid & 63) == 0) partials[blockIdx.x * 4 + (tid >> 6)] = csum;
}

// ---------------------------------------------------------------------------
// K6: vq_loss (sum of 16384 wave partials) + perplexity
// ---------------------------------------------------------------------------
__global__ void finalize_kernel(const float* __restrict__ ema,
                                const double* __restrict__ partials,
                                float* __restrict__ out) {
  __shared__ double red[256];
  const int t = threadIdx.x;

  double cs = 0.0;
  for (int i = t; i < 16384; i += 256) cs += partials[i];
  red[t] = cs;
  __syncthreads();
  for (int off = 128; off > 0; off >>= 1) {
    if (t < off) red[t] += red[t + off];
    __syncthreads();
  }
  double commit = red[0];
  __syncthreads();

  double s = 0.0;
  for (int i = t; i < K_CODES; i += 256) s += (double)(ema[i] + 1e-10f);
  red[t] = s;
  __syncthreads();
  for (int off = 128; off > 0; off >>= 1) {
    if (t < off) red[t] += red[t + off];
    __syncthreads();
  }
  double S = red[0];
  __syncthreads();

  double h = 0.0;
  for (int i = t; i < K_CODES; i += 256) {
    float p = (float)((ema[i] + 1e-10f) / (float)S);
    h += (double)(p * logf(p));
  }
  red[t] = h;
  __syncthreads();
  for (int off = 128; off > 0; off >>= 1) {
    if (t < off) red[t] += red[t + off];
    __syncthreads();
  }

  if (t == 0) {
    out[OFF_SCAL]     = 0.25f * (float)(commit / (double)((size_t)M_ROWS * (size_t)D_DIM));
    out[OFF_SCAL + 1] = expf((float)(-red[0]));
  }
}

extern "C" void kernel_launch(void* const* d_in, const int* in_sizes, int n_in,
                              void* d_out, int out_size, void* d_ws, size_t ws_size,
                              hipStream_t stream) {
  (void)in_sizes; (void)n_in; (void)out_size;
  const float* z_e = (const float*)d_in[0];
  const float* cb  = (const float*)d_in[1];
  const float* ema = (const float*)d_in[2];
  float* out = (float*)d_out;

  // d_ws layout
  int*    cnt      = (int*)d_ws;                            // @0, zeroed
  int*    alist    = (int*)((char*)d_ws + 1024);            // 256 KB
  float*  e2       = (float*)((char*)d_ws + 263168);        // 16 KB
  double* partials = (double*)((char*)d_ws + 279552);       // 128 KB -> ends 410624
  char*   img      = (char*)d_out + IMG_OFF;                // 1 MB (z_q_st region scratch)
  float*  e2b      = (float*)((char*)d_out + E2B_OFF);      // 16 KB

  const size_t cand_bytes = (size_t)M_ROWS * 16 * 8;        // 8 MB
  const int use_ws = (ws_size >= 417792 + cand_bytes) ? 1 : 0;
  u64* cand64 = use_ws
      ? (u64*)((char*)d_ws + 417792)
      : (u64*)((char*)d_out + CANDB_OFF);                   // z_q region (overwritten by zq_kernel)

  (void)hipMemsetAsync(d_ws, 0, 256, stream);
  e2_kernel<<<K_CODES / 256, 256, 0, stream>>>(cb, e2, e2b);
  img_kernel<<<(K_CODES * D_DIM / 4) / 256, 256, 0, stream>>>(cb, img);
  vq_mfma_kernel<<<(M_ROWS / 512) * NSPLIT, 512, 0, stream>>>(z_e, img, e2b, cand64);
  pick_kernel<<<M_ROWS / 256, 256, 0, stream>>>(cand64, out, cnt, alist);
  resolve_kernel<<<M_ROWS / 256, 256, 0, stream>>>(z_e, cb, e2, cand64, alist, cnt, out);
  zq_kernel<<<M_ROWS * 16 / 256, 256, 0, stream>>>(z_e, cb, out, partials);
  finalize_kernel<<<1, 256, 0, stream>>>(ema, partials, out);
}

// Round 11
// 231.685 us; speedup vs baseline: 1.1730x; 1.1730x over previous
//
#include <hip/hip_runtime.h>
#include <cmath>

#define M_ROWS  65536
#define D_DIM   64
#define K_CODES 4096

// d_out float offsets (z_q_st | indices | vq_loss | perplexity | z_q)
#define OFF_IDX  4194304
#define OFF_SCAL 4259840
#define OFF_ZQ   4259842

// scratch regions inside d_out (consumed before their region is written)
#define IMG_OFF   (4u << 20)                 // codebook image, 1 MB (in z_q_st region)
#define CANDB_OFF 17039368u                  // == OFF_ZQ*4 : fallback cand64 (8 MB; read by pick, then overwritten by zq)

// codebook chunk image: 128 codes, bf16 hi/lo split, 128 B/row, XOR-swizzled granules
#define CH_LO    16384
#define CH_BYTES 32768
#define CH_QUADS 2048
#define NSPLIT   4
#define NCHB     8                            // chunks per block (1024 codes)

typedef __attribute__((ext_vector_type(8))) short s16x8;
typedef __attribute__((ext_vector_type(4))) float f32x4;
typedef unsigned long long u64;

__device__ __forceinline__ unsigned short f2bf(float f) {   // RNE float->bf16 bits
  unsigned int u = __float_as_uint(f);
  return (unsigned short)((u + 0x7FFFu + ((u >> 16) & 1u)) >> 16);
}
__device__ __forceinline__ float bf2f(unsigned short h) {
  return __uint_as_float(((unsigned int)h) << 16);
}
__device__ __forceinline__ unsigned int umin_(unsigned int a, unsigned int b) {
  return a < b ? a : b;
}
// second-min update: with invariant b1 <= b2, new b2 = median(old b1, b2, key)
__device__ __forceinline__ unsigned int med3_u32(unsigned int a, unsigned int b, unsigned int c) {
  unsigned int d;
  asm("v_med3_u32 %0, %1, %2, %3" : "=v"(d) : "v"(a), "v"(b), "v"(c));
  return d;
}

// exact distance with the numpy-matched formula (verified r2..r10)
__device__ __forceinline__ float exact_dist(const float4* z4, float z2,
                                            const float* __restrict__ cb,
                                            const float* __restrict__ e2, int k) {
  const float4* ev = (const float4*)(cb + (size_t)k * 64);
  float4 a0 = make_float4(0.f, 0.f, 0.f, 0.f);
  float4 a1 = make_float4(0.f, 0.f, 0.f, 0.f);
  float4 a2 = make_float4(0.f, 0.f, 0.f, 0.f);
  float4 a3 = make_float4(0.f, 0.f, 0.f, 0.f);
#pragma unroll
  for (int q = 0; q < 4; ++q) {
    float4 e0 = ev[4 * q + 0], e1 = ev[4 * q + 1], e2v = ev[4 * q + 2], e3 = ev[4 * q + 3];
    a0.x = fmaf(z4[4 * q + 0].x, e0.x, a0.x); a0.y = fmaf(z4[4 * q + 0].y, e0.y, a0.y);
    a0.z = fmaf(z4[4 * q + 0].z, e0.z, a0.z); a0.w = fmaf(z4[4 * q + 0].w, e0.w, a0.w);
    a1.x = fmaf(z4[4 * q + 1].x, e1.x, a1.x); a1.y = fmaf(z4[4 * q + 1].y, e1.y, a1.y);
    a1.z = fmaf(z4[4 * q + 1].z, e1.z, a1.z); a1.w = fmaf(z4[4 * q + 1].w, e1.w, a1.w);
    a2.x = fmaf(z4[4 * q + 2].x, e2v.x, a2.x); a2.y = fmaf(z4[4 * q + 2].y, e2v.y, a2.y);
    a2.z = fmaf(z4[4 * q + 2].z, e2v.z, a2.z); a2.w = fmaf(z4[4 * q + 2].w, e2v.w, a2.w);
    a3.x = fmaf(z4[4 * q + 3].x, e3.x, a3.x); a3.y = fmaf(z4[4 * q + 3].y, e3.y, a3.y);
    a3.z = fmaf(z4[4 * q + 3].z, e3.z, a3.z); a3.w = fmaf(z4[4 * q + 3].w, e3.w, a3.w);
  }
  float d;
  {
#pragma clang fp contract(off)
    float sx = (a0.x + a1.x) + (a2.x + a3.x);
    float sy = (a0.y + a1.y) + (a2.y + a3.y);
    float sz = (a0.z + a1.z) + (a2.z + a3.z);
    float sw = (a0.w + a1.w) + (a2.w + a3.w);
    float dot = (sx + sy) + (sz + sw);
    float tt = z2 + e2[k];
    d = tt - 2.0f * dot;
  }
  return d;
}

__device__ __forceinline__ float exact_z2(const float4* z4) {
#pragma clang fp contract(off)
  float rr[8];
  {
    const float* f = (const float*)&z4[0];
#pragma unroll
    for (int j = 0; j < 8; ++j) rr[j] = f[j] * f[j];
  }
#pragma unroll
  for (int a = 1; a < 8; ++a) {
    const float* f = (const float*)&z4[2 * a];
#pragma unroll
    for (int j = 0; j < 8; ++j) rr[j] = rr[j] + f[j] * f[j];
  }
  return ((rr[0] + rr[1]) + (rr[2] + rr[3])) + ((rr[4] + rr[5]) + (rr[6] + rr[7]));
}

// ---------------------------------------------------------------------------
// K1: prep — bf16 hi/lo split image (coalesced) + e2/e2b (numpy-exact) fused.
// ---------------------------------------------------------------------------
__global__ void prep_kernel(const float* __restrict__ cb, char* __restrict__ img,
                            float* __restrict__ e2, float* __restrict__ e2b) {
  int t = blockIdx.x * 256 + threadIdx.x;   // 65536 threads, 4 elements each
  {
    int k  = t >> 4;
    int d0 = (t & 15) * 4;
    float4 f = ((const float4*)cb)[t];
    ushort4 hi, lo;
    hi.x = f2bf(f.x); lo.x = f2bf(f.x - bf2f(hi.x));
    hi.y = f2bf(f.y); lo.y = f2bf(f.y - bf2f(hi.y));
    hi.z = f2bf(f.z); lo.z = f2bf(f.z - bf2f(hi.z));
    hi.w = f2bf(f.w); lo.w = f2bf(f.w - bf2f(hi.w));
    int c = k >> 7, r = k & 127;
    int g = d0 >> 3;
    int off = ((g + r) & 7) * 16 + (d0 & 7) * 2;
    char* base = img + (size_t)c * CH_BYTES + r * 128;
    *(ushort4*)(base + off) = hi;
    *(ushort4*)(base + CH_LO + off) = lo;
  }
  if (t < K_CODES) {                         // blocks 0..15 also compute e2
    const float4* row = (const float4*)(cb + (size_t)t * D_DIM);
    float4 q[16];
#pragma unroll
    for (int i = 0; i < 16; ++i) q[i] = row[i];
    float s = exact_z2(q);
    e2[t] = s;
    e2b[t] = s + 32.0f;
  }
}

// ---------------------------------------------------------------------------
// K2: MFMA distance pass — round-6 measured-best body (NSPLIT 4, 512 thr,
// grid 512, 64 VGPR no spill). Store: ROW-MAJOR u64, 32 B/thread contiguous:
// cand64[grow*16 + sp*4 + i] = key<<32 | k.
// ---------------------------------------------------------------------------
__global__ __launch_bounds__(512, 4)
void vq_mfma_kernel(const float* __restrict__ z_e,
                    const char* __restrict__ img,
                    const float* __restrict__ e2b,
                    u64* __restrict__ cand64) {
  __shared__ union {
    uint4 q[CH_QUADS];
    char raw[CH_BYTES];
    unsigned int cand[256 * 33];     // 33792 B
  } sm;
  __shared__ float lds_e2[128];
  const int tid  = threadIdx.x;
  const int wave = tid >> 6, lane = tid & 63;
  const int quad = lane >> 4, c16 = lane & 15;
  const int rb   = blockIdx.x >> 2;           // row-group of 512
  const int sp   = blockIdx.x & 3;            // K-split id
  const int mb   = rb * 512 + wave * 64;

  // A-fragments: 4 row-tiles x (k-halves) x (hi/lo), A[m=lane&15][k=quad*8+j]
  s16x8 zh[4][2], zl[4][2];
#pragma unroll
  for (int mt = 0; mt < 4; ++mt) {
    int m = mb + mt * 16 + c16;
#pragma unroll
    for (int s = 0; s < 2; ++s) {
      const float* zp = z_e + (size_t)m * 64 + s * 32 + quad * 8;
      float4 fa = ((const float4*)zp)[0];
      float4 fb = ((const float4*)zp)[1];
      float v[8] = {fa.x, fa.y, fa.z, fa.w, fb.x, fb.y, fb.z, fb.w};
      union { s16x8 v8; unsigned short e[8]; } H, L;
#pragma unroll
      for (int j = 0; j < 8; ++j) {
        float f = -2.0f * v[j];
        unsigned short h = f2bf(f);
        H.e[j] = h;
        L.e[j] = f2bf(f - bf2f(h));
      }
      zh[mt][s] = H.v8;
      zl[mt][s] = L.v8;
    }
  }

  unsigned int b1[4][4], b2[4][4];
#pragma unroll
  for (int mt = 0; mt < 4; ++mt)
#pragma unroll
    for (int r = 0; r < 4; ++r) { b1[mt][r] = 0xFFFFFFFFu; b2[mt][r] = 0xFFFFFFFFu; }

  const int swz0 = ((quad + c16) & 7) * 16;       // t-invariant swizzle offsets
  const int swz1 = ((quad + 4 + c16) & 7) * 16;

  for (int c = 0; c < NCHB; ++c) {
    __syncthreads();
    {
      const uint4* src = (const uint4*)(img + (size_t)(sp * NCHB + c) * CH_BYTES);
#pragma unroll
      for (int i = 0; i < 4; ++i) sm.q[tid + i * 512] = src[tid + i * 512];
      if (tid < 128) lds_e2[tid] = e2b[sp * 1024 + c * 128 + tid];
    }
    __syncthreads();

#pragma unroll 1
    for (int t = 0; t < 8; ++t) {
      const char* hb = sm.raw + (t * 16 + c16) * 128;
      s16x8 Bh0 = *(const s16x8*)(hb + swz0);
      s16x8 Bh1 = *(const s16x8*)(hb + swz1);
      s16x8 Bl0 = *(const s16x8*)(hb + CH_LO + swz0);
      s16x8 Bl1 = *(const s16x8*)(hb + CH_LO + swz1);
      float e2v = lds_e2[t * 16 + c16];
      unsigned int tid8 = (unsigned int)(sp * 64 + c * 8 + t);  // global 16-code tile id
      f32x4 cvec = {e2v, e2v, e2v, e2v};

#pragma unroll
      for (int mt = 0; mt < 4; ++mt) {
        f32x4 acc;
        acc = __builtin_amdgcn_mfma_f32_16x16x32_bf16(zh[mt][0], Bh0, cvec, 0, 0, 0);
        acc = __builtin_amdgcn_mfma_f32_16x16x32_bf16(zh[mt][1], Bh1, acc, 0, 0, 0);
        acc = __builtin_amdgcn_mfma_f32_16x16x32_bf16(zl[mt][0], Bh0, acc, 0, 0, 0);
        acc = __builtin_amdgcn_mfma_f32_16x16x32_bf16(zl[mt][1], Bh1, acc, 0, 0, 0);
        acc = __builtin_amdgcn_mfma_f32_16x16x32_bf16(zh[mt][0], Bl0, acc, 0, 0, 0);
        acc = __builtin_amdgcn_mfma_f32_16x16x32_bf16(zh[mt][1], Bl1, acc, 0, 0, 0);
#pragma unroll
        for (int r = 0; r < 4; ++r) {
          unsigned int key = (__float_as_uint(acc[r]) & 0xFFFFFF00u) | tid8;
          b2[mt][r] = med3_u32(b1[mt][r], b2[mt][r], key);
          b1[mt][r] = umin_(b1[mt][r], key);
        }
      }
    }
  }

  // final selection: two passes of 256 rows through the cand buffer
  for (int pass = 0; pass < 2; ++pass) {
    __syncthreads();
    if ((wave >> 2) == pass) {
      int wl = wave & 3;
#pragma unroll
      for (int mt = 0; mt < 4; ++mt)
#pragma unroll
        for (int r = 0; r < 4; ++r) {
          int lr = wl * 64 + mt * 16 + quad * 4 + r;   // C: col=lane&15, row=quad*4+reg
          sm.cand[lr * 33 + c16 * 2 + 0] = b1[mt][r];
          sm.cand[lr * 33 + c16 * 2 + 1] = b2[mt][r];
        }
    }
    __syncthreads();
    if (tid < 256) {
      unsigned int kk[4] = {0xFFFFFFFFu, 0xFFFFFFFFu, 0xFFFFFFFFu, 0xFFFFFFFFu};
      unsigned int vv[4] = {0, 0, 0, 0};
      for (int j = 0; j < 32; ++j) {
        unsigned int key = sm.cand[tid * 33 + j];
        if (key < kk[3]) {
          kk[3] = key;
          vv[3] = (key & 0xFFu) * 16 + (unsigned int)(j >> 1);  // k = tile*16 + col
          for (int p = 3; p > 0; --p)
            if (kk[p] < kk[p - 1]) {
              unsigned int a = kk[p]; kk[p] = kk[p - 1]; kk[p - 1] = a;
              unsigned int b = vv[p]; vv[p] = vv[p - 1]; vv[p - 1] = b;
            }
        }
      }
      int grow = rb * 512 + pass * 256 + tid;
#pragma unroll
      for (int i = 0; i < 4; ++i)
        cand64[(size_t)grow * 16 + sp * 4 + i] = ((u64)kk[i] << 32) | (u64)vv[i];
    }
  }
}

// ---------------------------------------------------------------------------
// K3: pick+resolve fused. One thread/row: top-4 of 16 u64 cands, gap gate
// (4 quanta); gated rows write idx directly. Ambiguous rows compacted into an
// LDS list (LDS atomic); after a barrier the first lcnt threads resolve them
// with the exact formula. No global atomics, no memset dependency.
// ---------------------------------------------------------------------------
__global__ __launch_bounds__(256)
void pick_kernel(const float* __restrict__ z_e, const float* __restrict__ cb,
                 const float* __restrict__ e2, const u64* __restrict__ cand64,
                 float* __restrict__ out) {
  __shared__ int list[256];
  __shared__ int lcnt;
  const int tid = threadIdx.x;
  const int r   = blockIdx.x * 256 + tid;
  if (tid == 0) lcnt = 0;
  __syncthreads();

  u64 t4[4] = {~0ull, ~0ull, ~0ull, ~0ull};
#pragma unroll 1
  for (int j = 0; j < 16; ++j) {
    u64 v = cand64[(size_t)r * 16 + j];
    if (v < t4[3]) {
      t4[3] = v;
#pragma unroll
      for (int p = 3; p > 0; --p)
        if (t4[p] < t4[p - 1]) { u64 a = t4[p]; t4[p] = t4[p - 1]; t4[p - 1] = a; }
    }
  }

  unsigned int key1 = (unsigned int)(t4[0] >> 32) & 0xFFFFFF00u;
  unsigned int key2 = (unsigned int)(t4[1] >> 32) & 0xFFFFFF00u;
  bool ambig = (key2 - key1) < 1024u;             // < 4 quanta
  if (!ambig) {
    out[OFF_IDX + r] = (float)(unsigned int)(t4[0] & 0xFFFFFFFFu);
  } else {
    list[atomicAdd(&lcnt, 1)] = tid;              // row-local id
  }
  __syncthreads();

  int n = lcnt;
  if (tid < n) {
    int rr = blockIdx.x * 256 + list[tid];
    u64 s4[4] = {~0ull, ~0ull, ~0ull, ~0ull};
#pragma unroll 1
    for (int j = 0; j < 16; ++j) {
      u64 v = cand64[(size_t)rr * 16 + j];
      if (v < s4[3]) {
        s4[3] = v;
#pragma unroll
        for (int p = 3; p > 0; --p)
          if (s4[p] < s4[p - 1]) { u64 a = s4[p]; s4[p] = s4[p - 1]; s4[p - 1] = a; }
      }
    }
    const float4* zr = (const float4*)(z_e + (size_t)rr * 64);
    float4 z4[16];
#pragma unroll
    for (int j = 0; j < 16; ++j) z4[j] = zr[j];
    float z2 = exact_z2(z4);

    float bd = INFINITY;
    int bk = K_CODES;
#pragma unroll 1
    for (int ci = 0; ci < 4; ++ci) {
      int k = (int)(unsigned int)(s4[ci] & 0xFFFFFFFFu);
      float d = exact_dist(z4, z2, cb, e2, k);
      if (d < bd || (d == bd && k < bk)) { bd = d; bk = k; }
    }
    out[OFF_IDX + rr] = (float)bk;
  }
}

// ---------------------------------------------------------------------------
// K4: zq. 16 lanes per row: idx broadcast-read, winner gather is 4 cb rows
// per wave-inst, z read + both outputs coalesced. Commit partials (all slots
// written unconditionally -> no memset needed).
// ---------------------------------------------------------------------------
__global__ __launch_bounds__(256)
void zq_kernel(const float* __restrict__ z_e, const float* __restrict__ cb,
               float* __restrict__ out, double* __restrict__ partials) {
  const int tid = threadIdx.x;
  const int t   = blockIdx.x * 256 + tid;
  const int m   = t >> 4, seg = t & 15;

  int k = (int)out[OFF_IDX + m];
  float4 q = *(const float4*)(cb + (size_t)k * 64 + seg * 4);
  float4 z = *(const float4*)(z_e + (size_t)m * 64 + seg * 4);

  ((float4*)out)[(size_t)m * 16 + seg] = q;            // z_q_st
  float* d1 = out + OFF_ZQ + (size_t)m * 64 + seg * 4; // z_q (8B-aligned)
  ((float2*)d1)[0] = make_float2(q.x, q.y);
  ((float2*)d1)[1] = make_float2(q.z, q.w);

  float dx = z.x - q.x, dy = z.y - q.y, dz = z.z - q.z, dw = z.w - q.w;
  double csum = (double)dx * dx + (double)dy * dy + (double)dz * dz + (double)dw * dw;
#pragma unroll
  for (int off = 32; off > 0; off >>= 1) csum += __shfl_down(csum, off);
  if ((tid & 63) == 0) partials[blockIdx.x * 4 + (tid >> 6)] = csum;
}

// ---------------------------------------------------------------------------
// K5: vq_loss (sum of 16384 wave partials) + perplexity
// ---------------------------------------------------------------------------
__global__ void finalize_kernel(const float* __restrict__ ema,
                                const double* __restrict__ partials,
                                float* __restrict__ out) {
  __shared__ double red[256];
  const int t = threadIdx.x;

  double cs = 0.0;
  for (int i = t; i < 16384; i += 256) cs += partials[i];
  red[t] = cs;
  __syncthreads();
  for (int off = 128; off > 0; off >>= 1) {
    if (t < off) red[t] += red[t + off];
    __syncthreads();
  }
  double commit = red[0];
  __syncthreads();

  double s = 0.0;
  for (int i = t; i < K_CODES; i += 256) s += (double)(ema[i] + 1e-10f);
  red[t] = s;
  __syncthreads();
  for (int off = 128; off > 0; off >>= 1) {
    if (t < off) red[t] += red[t + off];
    __syncthreads();
  }
  double S = red[0];
  __syncthreads();

  double h = 0.0;
  for (int i = t; i < K_CODES; i += 256) {
    float p = (float)((ema[i] + 1e-10f) / (float)S);
    h += (double)(p * logf(p));
  }
  red[t] = h;
  __syncthreads();
  for (int off = 128; off > 0; off >>= 1) {
    if (t < off) red[t] += red[t + off];
    __syncthreads();
  }

  if (t == 0) {
    out[OFF_SCAL]     = 0.25f * (float)(commit / (double)((size_t)M_ROWS * (size_t)D_DIM));
    out[OFF_SCAL + 1] = expf((float)(-red[0]));
  }
}

extern "C" void kernel_launch(void* const* d_in, const int* in_sizes, int n_in,
                              void* d_out, int out_size, void* d_ws, size_t ws_size,
                              hipStream_t stream) {
  (void)in_sizes; (void)n_in; (void)out_size;
  const float* z_e = (const float*)d_in[0];
  const float* cb  = (const float*)d_in[1];
  const float* ema = (const float*)d_in[2];
  float* out = (float*)d_out;

  // d_ws layout: e2 @0 (16K) | e2b @16K (16K) | partials @32K (128K) | cand64 @160K
  float*  e2       = (float*)d_ws;
  float*  e2b      = (float*)((char*)d_ws + 16384);
  double* partials = (double*)((char*)d_ws + 32768);        // 16384 doubles
  char*   img      = (char*)d_out + IMG_OFF;                // 1 MB (z_q_st region scratch)

  const size_t cand_bytes = (size_t)M_ROWS * 16 * 8;        // 8 MB
  const int use_ws = (ws_size >= 163840 + cand_bytes) ? 1 : 0;
  u64* cand64 = use_ws
      ? (u64*)((char*)d_ws + 163840)
      : (u64*)((char*)d_out + CANDB_OFF);   // z_q region: read by pick, overwritten later by zq — stream-ordered, safe

  prep_kernel<<<(K_CODES * D_DIM / 4) / 256, 256, 0, stream>>>(cb, img, e2, e2b);
  vq_mfma_kernel<<<(M_ROWS / 512) * NSPLIT, 512, 0, stream>>>(z_e, img, e2b, cand64);
  pick_kernel<<<M_ROWS / 256, 256, 0, stream>>>(z_e, cb, e2, cand64, out);
  zq_kernel<<<M_ROWS * 16 / 256, 256, 0, stream>>>(z_e, cb, out, partials);
  finalize_kernel<<<1, 256, 0, stream>>>(ema, partials, out);
}